// Round 10
// baseline (1305.516 us; speedup 1.0000x reference)
//
#include <hip/hip_runtime.h>

#define NPTS 8192
#define HDIM 64
#define KNN 16
#define LOG2E 1.4426950408889634f

// exp(x) via raw v_exp_f32 (2^y). ~1 ulp; s_nop covers the trans-op hazard.
__device__ __forceinline__ float fast_exp(float x) {
    float y = x * LOG2E;
    float r;
    asm volatile("v_exp_f32 %0, %1\n\ts_nop 1" : "=v"(r) : "v"(y));
    return r;
}

// ws_size probes — dispatch list on a PASS tells us the workspace budget.
__global__ void ws_marker_ge2mb(char* p)  { if (threadIdx.x == 0) p[0] = 1; }
__global__ void ws_marker_ge16mb(char* p) { if (threadIdx.x == 0) p[1] = 1; }
__global__ void ws_marker_ge64mb(char* p) { if (threadIdx.x == 0) p[2] = 1; }

// ---------------------------------------------------------------------------
// Fused kernel, FLOAT32 I/O (reference dtype — the R1-R9 aborts were NaN
// distances from a bf16 misread -> sentinel neighbor idx -> wild address).
// One wave per point, 4 waves/block.
// LDS: Wk/Wks/Wv staged as f32 (48 KB). Wp2/Wt1/Wt2 from global (L2-hot).
// ---------------------------------------------------------------------------
__global__ __launch_bounds__(256) void LocalTransformer_80513456931527_kernel(
    const float* __restrict__ xyzp, const float* __restrict__ features,
    const float* __restrict__ Wk, const float* __restrict__ bk,
    const float* __restrict__ Wq, const float* __restrict__ Wks,
    const float* __restrict__ Wv,
    const float* __restrict__ Wp1, const float* __restrict__ bp1,
    const float* __restrict__ Wp2, const float* __restrict__ bp2,
    const float* __restrict__ Wt1, const float* __restrict__ bt1,
    const float* __restrict__ Wt2, const float* __restrict__ bt2,
    const float* __restrict__ Wa,  const float* __restrict__ ba,
    float* __restrict__ out)
{
    __shared__ __align__(16) float sWk[4096], sWks[4096], sWv[4096];  // 48 KB

    int tid = threadIdx.x, w = tid >> 6, lane = tid & 63;
    for (int i = tid; i < 4096; i += 256) {
        sWk[i]  = Wk[i];
        sWks[i] = Wks[i];
        sWv[i]  = Wv[i];
    }
    __syncthreads();

    int p = blockIdx.x * 4 + w;                 // 0 .. 16383
    int b = p >> 13;
    int n = p & (NPTS - 1);
    const float4* xb4 = (const float4*)(xyzp + (size_t)b * NPTS * 4);

    // ---------------- Phase 1: KNN top-16 ----------------
    float4 self = xb4[n];
    float qx = self.x, qy = self.y, qz = self.z;
    float qs = qx * qx + qy * qy + qz * qz;

    float dh[16]; int ih[16];
    #pragma unroll
    for (int j = 0; j < 16; ++j) { dh[j] = 3.4e38f; ih[j] = 0x7fffffff; }

    for (int t = 0; t < NPTS / 64; ++t) {
        int m = t * 64 + lane;
        float4 c4 = xb4[m];
        float cs = c4.x * c4.x + c4.y * c4.y + c4.z * c4.z;
        float d = qs + cs - 2.0f * (qx * c4.x + qy * c4.y + qz * c4.z);
        if (d < dh[15]) {               // strict <: ties keep lower index
            dh[15] = d; ih[15] = m;
            #pragma unroll
            for (int j = 15; j >= 1; --j) {
                if (dh[j] < dh[j - 1]) {
                    float td = dh[j]; dh[j] = dh[j - 1]; dh[j - 1] = td;
                    int   ti = ih[j]; ih[j] = ih[j - 1]; ih[j - 1] = ti;
                }
            }
        }
    }
    // 16-round wave argmin merge with winner-shift (registers + shfl only)
    int mynb = 0;                       // lane r ends holding neighbor r
    #pragma unroll 1
    for (int r = 0; r < KNN; ++r) {
        float d = dh[0]; int i = ih[0];
        #pragma unroll
        for (int s = 1; s < 64; s <<= 1) {
            float d2 = __shfl_xor(d, s); int i2 = __shfl_xor(i, s);
            if (d2 < d || (d2 == d && i2 < i)) { d = d2; i = i2; }
        }
        if (lane == r) mynb = i;
        if (ih[0] == i) {               // unique winner (per-lane sets disjoint)
            #pragma unroll
            for (int j = 0; j < 15; ++j) { dh[j] = dh[j + 1]; ih[j] = ih[j + 1]; }
            dh[15] = 3.4e38f; ih[15] = 0x7fffffff;
        }
    }
    // structural safety: wild neighbor index can shift values, never fault
    mynb = min(max(mynb, 0), NPTS - 1);

    // ---------------- Phase 2: self x, q ----------------
    float bk_r  = bk[lane];
    float bp1_r = bp1[lane], bp2_r = bp2[lane];
    float bt1_r = bt1[lane], bt2_r = bt2[lane];
    float ba_r  = ba[lane];
    float wp1_0 = Wp1[0 * 64 + lane], wp1_1 = Wp1[1 * 64 + lane];
    float wp1_2 = Wp1[2 * 64 + lane], wp1_3 = Wp1[3 * 64 + lane];

    float f = features[(size_t)p * HDIM + lane];
    float x = bk_r;
    #pragma unroll 8
    for (int c = 0; c < 64; ++c)
        x += __shfl(f, c) * sWk[c * 64 + lane];
    float q = 0.f;
    #pragma unroll 8
    for (int c = 0; c < 64; ++c)
        q += __shfl(x, c) * Wq[c * 64 + lane];          // Wq used once: global
    float xq = (lane < 4) ? xyzp[(size_t)p * 4 + lane] : 0.f;

    // ---------------- Phase 3: neighbors, online softmax ----------------
    float sm_m = -3.4e38f, sm_s = 0.f, sm_r = 0.f;
    #pragma unroll 1
    for (int j = 0; j < KNN; ++j) {
        int m  = __shfl(mynb, j);
        int nb = b * NPTS + m;
        float fm = features[(size_t)nb * HDIM + lane];
        float xm = bk_r;
        #pragma unroll 8
        for (int c = 0; c < 64; ++c)
            xm += __shfl(fm, c) * sWk[c * 64 + lane];
        float km = 0.f, vm = 0.f;
        #pragma unroll 8
        for (int c = 0; c < 64; ++c) {
            float xc = __shfl(xm, c);
            km += xc * sWks[c * 64 + lane];
            vm += xc * sWv[c * 64 + lane];
        }
        float xn  = (lane < 4) ? xyzp[(size_t)nb * 4 + lane] : 0.f;
        float rel = xq - xn;
        float a = bp1_r + __shfl(rel, 0) * wp1_0 + __shfl(rel, 1) * wp1_1
                        + __shfl(rel, 2) * wp1_2 + __shfl(rel, 3) * wp1_3;
        float pe1 = fmaxf(a, 0.f);
        float pe2 = bp2_r;
        #pragma unroll 8
        for (int c = 0; c < 64; ++c)
            pe2 += __shfl(pe1, c) * Wp2[c * 64 + lane]; // global, L2-hot
        float ah = q - km + pe2;
        float t1 = bt1_r;
        #pragma unroll 8
        for (int c = 0; c < 64; ++c)
            t1 += __shfl(ah, c) * Wt1[c * 64 + lane];   // global, L2-hot
        t1 = fmaxf(t1, 0.f);
        float lg = bt2_r;
        #pragma unroll 8
        for (int c = 0; c < 64; ++c)
            lg += __shfl(t1, c) * Wt2[c * 64 + lane];   // global, L2-hot
        lg *= 0.125f;                   // / sqrt(64)
        float vp = vm + pe2;
        float nm = fmaxf(sm_m, lg);
        float ea = fast_exp(sm_m - nm);
        float eb = fast_exp(lg - nm);
        sm_s = sm_s * ea + eb;
        sm_r = sm_r * ea + eb * vp;
        sm_m = nm;
    }

    // ---------------- Phase 4: output projection + residual ----------------
    float res = sm_r / sm_s;
    float o = ba_r;
    #pragma unroll 8
    for (int c = 0; c < 64; ++c)
        o += __shfl(res, c) * Wa[c * 64 + lane];        // global, once
    out[(size_t)p * HDIM + lane] = o + f;
}

// ---------------------------------------------------------------------------
extern "C" void kernel_launch(void* const* d_in, const int* in_sizes, int n_in,
                              void* d_out, int out_size, void* d_ws, size_t ws_size,
                              hipStream_t stream)
{
    (void)in_sizes; (void)n_in; (void)out_size;
    // dict order: xyzp, features, Wk, bk, Wq, Wks, Wv, Wp1, bp1, Wp2, bp2,
    //             Wt1, bt1, Wt2, bt2, Wa, ba, (k_nearest) — ALL FLOAT32.
    const float* xyzp     = (const float*)d_in[0];
    const float* features = (const float*)d_in[1];
    const float* Wk  = (const float*)d_in[2];
    const float* bk  = (const float*)d_in[3];
    const float* Wq  = (const float*)d_in[4];
    const float* Wks = (const float*)d_in[5];
    const float* Wv  = (const float*)d_in[6];
    const float* Wp1 = (const float*)d_in[7];
    const float* bp1 = (const float*)d_in[8];
    const float* Wp2 = (const float*)d_in[9];
    const float* bp2 = (const float*)d_in[10];
    const float* Wt1 = (const float*)d_in[11];
    const float* bt1 = (const float*)d_in[12];
    const float* Wt2 = (const float*)d_in[13];
    const float* bt2 = (const float*)d_in[14];
    const float* Wa  = (const float*)d_in[15];
    const float* ba  = (const float*)d_in[16];
    float* out = (float*)d_out;

    // ws budget probes (read from the rocprof dispatch list on a pass)
    char* ws = (char*)d_ws;
    if (ws_size >= ((size_t)2  << 20)) ws_marker_ge2mb <<<1, 64, 0, stream>>>(ws);
    if (ws_size >= ((size_t)16 << 20)) ws_marker_ge16mb<<<1, 64, 0, stream>>>(ws);
    if (ws_size >= ((size_t)64 << 20)) ws_marker_ge64mb<<<1, 64, 0, stream>>>(ws);

    LocalTransformer_80513456931527_kernel<<<(2 * NPTS) / 4, 256, 0, stream>>>(
        xyzp, features, Wk, bk, Wq, Wks, Wv,
        Wp1, bp1, Wp2, bp2, Wt1, bt1, Wt2, bt2, Wa, ba, out);
}

// Round 11
// 507.260 us; speedup vs baseline: 2.5737x; 2.5737x over previous
//
#include <hip/hip_runtime.h>

#define NPTS 8192
#define HDIM 64
#define KNN 16
#define LOG2E 1.4426950408889634f

typedef __attribute__((ext_vector_type(8))) short bf8_t;   // 8 bf16 (4 VGPRs)
typedef __attribute__((ext_vector_type(4))) float f4_t;    // MFMA C/D
#define MFMA16(a, b, c) __builtin_amdgcn_mfma_f32_16x16x32_bf16(a, b, c, 0, 0, 0)

__device__ __forceinline__ float fast_exp(float x) {
    float y = x * LOG2E;
    float r;
    asm volatile("v_exp_f32 %0, %1\n\ts_nop 1" : "=v"(r) : "v"(y));
    return r;
}
__device__ __forceinline__ unsigned short f2b(float x) {   // f32 -> bf16 RNE
    unsigned v = __float_as_uint(x);
    return (unsigned short)((v + 0x7FFFu + ((v >> 16) & 1u)) >> 16);
}

// ---------------------------------------------------------------------------
// Kernel A: pack Wp2/Wt1/Wt2 (f32, row-major [k][n]) into MFMA B-frag order:
// frag(s,t): lane l, elem j  <->  B[k=s*32+(l>>4)*8+j][n=t*16+(l&15)].
// dst ushort idx = st*4096 + (s*4+t)*512 + l*8 + j.
// ---------------------------------------------------------------------------
__global__ void prefrag_kernel(const float* __restrict__ Wp2,
                               const float* __restrict__ Wt1,
                               const float* __restrict__ Wt2,
                               unsigned short* __restrict__ dst)
{
    int i = blockIdx.x * 256 + threadIdx.x;
    if (i >= 3 * 4096) return;
    int st = i >> 12, e = i & 4095;
    const float* W = (st == 0) ? Wp2 : (st == 1) ? Wt1 : Wt2;
    int k = e >> 6, n = e & 63;
    int s = k >> 5, quad = (k >> 3) & 3, j = k & 7;
    int t = n >> 4, l = quad * 16 + (n & 15);
    dst[st * 4096 + (s * 4 + t) * 512 + l * 8 + j] = f2b(W[e]);
}

// ---------------------------------------------------------------------------
// Kernel B: per-point projections q/k/v (f32) into workspace.
// ---------------------------------------------------------------------------
__global__ __launch_bounds__(256) void proj_kernel(
    const float* __restrict__ feat,
    const float* __restrict__ Wk, const float* __restrict__ bk,
    const float* __restrict__ Wq, const float* __restrict__ Wks,
    const float* __restrict__ Wv,
    float* __restrict__ qw, float* __restrict__ kw, float* __restrict__ vw)
{
    int w = threadIdx.x >> 6, lane = threadIdx.x & 63;
    int p = blockIdx.x * 4 + w;
    float f = feat[(size_t)p * HDIM + lane];
    float x = bk[lane];
    #pragma unroll 8
    for (int c = 0; c < 64; ++c) x += __shfl(f, c) * Wk[c * 64 + lane];
    float q = 0.f, k = 0.f, v = 0.f;
    #pragma unroll 8
    for (int c = 0; c < 64; ++c) {
        float xc = __shfl(x, c);
        q += xc * Wq[c * 64 + lane];
        k += xc * Wks[c * 64 + lane];
        v += xc * Wv[c * 64 + lane];
    }
    qw[(size_t)p * HDIM + lane] = q;
    kw[(size_t)p * HDIM + lane] = k;
    vw[(size_t)p * HDIM + lane] = v;
}

// ---------------------------------------------------------------------------
// Kernel C (main): KNN (proven R10 code) + MFMA per-neighbor MLPs.
// One wave per point. C-layout: col=lane&15 (h'), row=(lane>>4)*4+reg (m).
// A-layout: m=lane&15, k=(lane>>4)*8+j. Softmax over m = 4 regs + xor16/32.
// ---------------------------------------------------------------------------
__global__ __launch_bounds__(256) void LocalTransformer_80513456931527_kernel(
    const float* __restrict__ xyzp, const float* __restrict__ features,
    const float* __restrict__ Wp1,  const float* __restrict__ bp1,
    const float* __restrict__ bp2,  const float* __restrict__ bt1,
    const float* __restrict__ bt2,
    const float* __restrict__ Wa,   const float* __restrict__ ba,
    const float* __restrict__ qw, const float* __restrict__ kw,
    const float* __restrict__ vw,
    const unsigned short* __restrict__ fragw,
    float* __restrict__ out)
{
    __shared__ __align__(16) float sBounce[4][16 * 68 + 4];   // 17.5 KB

    int tid = threadIdx.x, w = tid >> 6, lane = tid & 63;
    int p = blockIdx.x * 4 + w;
    int b = p >> 13;
    int n = p & (NPTS - 1);
    const float4* xb4 = (const float4*)(xyzp + (size_t)b * NPTS * 4);
    float* bb = sBounce[w];

    // ---------------- Phase 1: KNN (verbatim from R10, proven) -------------
    float4 self = xb4[n];
    float qx = self.x, qy = self.y, qz = self.z;
    float qs = qx * qx + qy * qy + qz * qz;
    float dh[16]; int ih[16];
    #pragma unroll
    for (int j = 0; j < 16; ++j) { dh[j] = 3.4e38f; ih[j] = 0x7fffffff; }
    for (int t = 0; t < NPTS / 64; ++t) {
        int m = t * 64 + lane;
        float4 c4 = xb4[m];
        float cs = c4.x * c4.x + c4.y * c4.y + c4.z * c4.z;
        float d = qs + cs - 2.0f * (qx * c4.x + qy * c4.y + qz * c4.z);
        if (d < dh[15]) {
            dh[15] = d; ih[15] = m;
            #pragma unroll
            for (int j = 15; j >= 1; --j) {
                if (dh[j] < dh[j - 1]) {
                    float td = dh[j]; dh[j] = dh[j - 1]; dh[j - 1] = td;
                    int   ti = ih[j]; ih[j] = ih[j - 1]; ih[j - 1] = ti;
                }
            }
        }
    }
    int mynb = 0;
    #pragma unroll 1
    for (int r = 0; r < KNN; ++r) {
        float d = dh[0]; int i = ih[0];
        #pragma unroll
        for (int s = 1; s < 64; s <<= 1) {
            float d2 = __shfl_xor(d, s); int i2 = __shfl_xor(i, s);
            if (d2 < d || (d2 == d && i2 < i)) { d = d2; i = i2; }
        }
        if (lane == r) mynb = i;
        if (ih[0] == i) {
            #pragma unroll
            for (int j = 0; j < 15; ++j) { dh[j] = dh[j + 1]; ih[j] = ih[j + 1]; }
            dh[15] = 3.4e38f; ih[15] = 0x7fffffff;
        }
    }
    mynb = min(max(mynb, 0), NPTS - 1);

    int quad = lane >> 4, l15 = lane & 15;
    int nb_a = __shfl(mynb, l15);               // A-layout row m = lane&15
    int nbm[4];
    #pragma unroll
    for (int r = 0; r < 4; ++r) nbm[r] = __shfl(mynb, quad * 4 + r);  // C rows

    // ---------------- Phase 2: pe1 directly in A-frag layout ----------------
    const float4 xq4 = *(const float4*)(xyzp + (size_t)p * 4);
    const float4 xn4 = *(const float4*)(xyzp + ((size_t)b * NPTS + nb_a) * 4);
    float rel0 = xq4.x - xn4.x, rel1 = xq4.y - xn4.y;
    float rel2 = xq4.z - xn4.z, rel3 = xq4.w - xn4.w;

    bf8_t pe1f[2];
    #pragma unroll
    for (int s = 0; s < 2; ++s) {
        int hb = s * 32 + quad * 8;
        float W0[8], W1[8], W2[8], W3[8], Bb[8];
        *(float4*)&W0[0] = *(const float4*)(Wp1 +       hb);
        *(float4*)&W0[4] = *(const float4*)(Wp1 +       hb + 4);
        *(float4*)&W1[0] = *(const float4*)(Wp1 +  64 + hb);
        *(float4*)&W1[4] = *(const float4*)(Wp1 +  64 + hb + 4);
        *(float4*)&W2[0] = *(const float4*)(Wp1 + 128 + hb);
        *(float4*)&W2[4] = *(const float4*)(Wp1 + 128 + hb + 4);
        *(float4*)&W3[0] = *(const float4*)(Wp1 + 192 + hb);
        *(float4*)&W3[4] = *(const float4*)(Wp1 + 192 + hb + 4);
        *(float4*)&Bb[0] = *(const float4*)(bp1 + hb);
        *(float4*)&Bb[4] = *(const float4*)(bp1 + hb + 4);
        #pragma unroll
        for (int j = 0; j < 8; ++j) {
            float a = Bb[j] + rel0 * W0[j] + rel1 * W1[j]
                            + rel2 * W2[j] + rel3 * W3[j];
            pe1f[s][j] = (short)f2b(fmaxf(a, 0.f));
        }
    }

    // ---------------- Phase 3: pe2 = pe1 @ Wp2 + bp2 (MFMA) ----------------
    const bf8_t* BW = (const bf8_t*)fragw;   // [st*512 + (s*4+t)*64 + lane]
    f4_t pe2c[4];
    #pragma unroll
    for (int t = 0; t < 4; ++t) {
        f4_t acc = {0.f, 0.f, 0.f, 0.f};
        acc = MFMA16(pe1f[0], BW[0 * 512 + (0 * 4 + t) * 64 + lane], acc);
        acc = MFMA16(pe1f[1], BW[0 * 512 + (1 * 4 + t) * 64 + lane], acc);
        float bias = bp2[t * 16 + l15];
        #pragma unroll
        for (int r = 0; r < 4; ++r) acc[r] += bias;
        pe2c[t] = acc;
    }

    // ---------------- Phase 4: a_in = q - k + pe2; vpe = v + pe2 -----------
    f4_t ainc[4], vpec[4];
    #pragma unroll
    for (int t = 0; t < 4; ++t) {
        float qv = qw[(size_t)p * HDIM + t * 16 + l15];
        #pragma unroll
        for (int r = 0; r < 4; ++r) {
            size_t nbo = ((size_t)b * NPTS + nbm[r]) * HDIM + t * 16 + l15;
            ainc[t][r] = qv - kw[nbo] + pe2c[t][r];
            vpec[t][r] = vw[nbo] + pe2c[t][r];
        }
    }

    // ---------------- Phase 5: bounce a_in C->A, t1 MFMA, bounce, lg -------
    #pragma unroll
    for (int t = 0; t < 4; ++t)
        #pragma unroll
        for (int r = 0; r < 4; ++r)
            bb[(quad * 4 + r) * 68 + t * 16 + l15] = ainc[t][r];
    asm volatile("s_waitcnt lgkmcnt(0)" ::: "memory");
    bf8_t af[2];
    #pragma unroll
    for (int s = 0; s < 2; ++s) {
        float tmp[8];
        *(float4*)&tmp[0] = *(const float4*)&bb[l15 * 68 + s * 32 + quad * 8];
        *(float4*)&tmp[4] = *(const float4*)&bb[l15 * 68 + s * 32 + quad * 8 + 4];
        #pragma unroll
        for (int j = 0; j < 8; ++j) af[s][j] = (short)f2b(tmp[j]);
    }

    f4_t t1c[4];
    #pragma unroll
    for (int t = 0; t < 4; ++t) {
        f4_t acc = {0.f, 0.f, 0.f, 0.f};
        acc = MFMA16(af[0], BW[1 * 512 + (0 * 4 + t) * 64 + lane], acc);
        acc = MFMA16(af[1], BW[1 * 512 + (1 * 4 + t) * 64 + lane], acc);
        float bias = bt1[t * 16 + l15];
        #pragma unroll
        for (int r = 0; r < 4; ++r) t1c[t][r] = fmaxf(acc[r] + bias, 0.f);
    }

    asm volatile("s_waitcnt lgkmcnt(0)" ::: "memory");
    #pragma unroll
    for (int t = 0; t < 4; ++t)
        #pragma unroll
        for (int r = 0; r < 4; ++r)
            bb[(quad * 4 + r) * 68 + t * 16 + l15] = t1c[t][r];
    asm volatile("s_waitcnt lgkmcnt(0)" ::: "memory");
    bf8_t tf[2];
    #pragma unroll
    for (int s = 0; s < 2; ++s) {
        float tmp[8];
        *(float4*)&tmp[0] = *(const float4*)&bb[l15 * 68 + s * 32 + quad * 8];
        *(float4*)&tmp[4] = *(const float4*)&bb[l15 * 68 + s * 32 + quad * 8 + 4];
        #pragma unroll
        for (int j = 0; j < 8; ++j) tf[s][j] = (short)f2b(tmp[j]);
    }

    f4_t lgc[4];
    #pragma unroll
    for (int t = 0; t < 4; ++t) {
        f4_t acc = {0.f, 0.f, 0.f, 0.f};
        acc = MFMA16(tf[0], BW[2 * 512 + (0 * 4 + t) * 64 + lane], acc);
        acc = MFMA16(tf[1], BW[2 * 512 + (1 * 4 + t) * 64 + lane], acc);
        float bias = bt2[t * 16 + l15];
        #pragma unroll
        for (int r = 0; r < 4; ++r) lgc[t][r] = (acc[r] + bias) * 0.125f;
    }

    // ---------------- Phase 6: softmax over m (4 regs + xor16/32) ----------
    float res[4];
    #pragma unroll
    for (int t = 0; t < 4; ++t) {
        float m0 = fmaxf(fmaxf(lgc[t][0], lgc[t][1]), fmaxf(lgc[t][2], lgc[t][3]));
        m0 = fmaxf(m0, __shfl_xor(m0, 16));
        m0 = fmaxf(m0, __shfl_xor(m0, 32));
        float e0 = fast_exp(lgc[t][0] - m0), e1 = fast_exp(lgc[t][1] - m0);
        float e2 = fast_exp(lgc[t][2] - m0), e3 = fast_exp(lgc[t][3] - m0);
        float sl = e0 + e1 + e2 + e3;
        float rl = e0 * vpec[t][0] + e1 * vpec[t][1]
                 + e2 * vpec[t][2] + e3 * vpec[t][3];
        sl += __shfl_xor(sl, 16); sl += __shfl_xor(sl, 32);
        rl += __shfl_xor(rl, 16); rl += __shfl_xor(rl, 32);
        res[t] = rl / sl;
    }

    // ---------------- Phase 7: out = res @ Wa + ba + features --------------
    float rh = (quad == 0) ? res[0] : (quad == 1) ? res[1]
             : (quad == 2) ? res[2] : res[3];     // lane c holds res[h=c]
    float f = features[(size_t)p * HDIM + lane];
    float o = ba[lane];
    #pragma unroll 8
    for (int c = 0; c < 64; ++c) o += __shfl(rh, c) * Wa[c * 64 + lane];
    out[(size_t)p * HDIM + lane] = o + f;
}

// ---------------------------------------------------------------------------
// Fallback: proven R10 fused kernel (used when ws_size < 12 MB + frag).
// ---------------------------------------------------------------------------
__global__ __launch_bounds__(256) void fused_fallback_kernel(
    const float* __restrict__ xyzp, const float* __restrict__ features,
    const float* __restrict__ Wk, const float* __restrict__ bk,
    const float* __restrict__ Wq, const float* __restrict__ Wks,
    const float* __restrict__ Wv,
    const float* __restrict__ Wp1, const float* __restrict__ bp1,
    const float* __restrict__ Wp2, const float* __restrict__ bp2,
    const float* __restrict__ Wt1, const float* __restrict__ bt1,
    const float* __restrict__ Wt2, const float* __restrict__ bt2,
    const float* __restrict__ Wa,  const float* __restrict__ ba,
    float* __restrict__ out)
{
    __shared__ __align__(16) float sWk[4096], sWks[4096], sWv[4096];
    int tid = threadIdx.x, w = tid >> 6, lane = tid & 63;
    for (int i = tid; i < 4096; i += 256) {
        sWk[i] = Wk[i]; sWks[i] = Wks[i]; sWv[i] = Wv[i];
    }
    __syncthreads();
    int p = blockIdx.x * 4 + w;
    int b = p >> 13, n = p & (NPTS - 1);
    const float4* xb4 = (const float4*)(xyzp + (size_t)b * NPTS * 4);
    float4 self = xb4[n];
    float qx = self.x, qy = self.y, qz = self.z;
    float qs = qx * qx + qy * qy + qz * qz;
    float dh[16]; int ih[16];
    #pragma unroll
    for (int j = 0; j < 16; ++j) { dh[j] = 3.4e38f; ih[j] = 0x7fffffff; }
    for (int t = 0; t < NPTS / 64; ++t) {
        int m = t * 64 + lane;
        float4 c4 = xb4[m];
        float cs = c4.x * c4.x + c4.y * c4.y + c4.z * c4.z;
        float d = qs + cs - 2.0f * (qx * c4.x + qy * c4.y + qz * c4.z);
        if (d < dh[15]) {
            dh[15] = d; ih[15] = m;
            #pragma unroll
            for (int j = 15; j >= 1; --j)
                if (dh[j] < dh[j - 1]) {
                    float td = dh[j]; dh[j] = dh[j - 1]; dh[j - 1] = td;
                    int ti = ih[j]; ih[j] = ih[j - 1]; ih[j - 1] = ti;
                }
        }
    }
    int mynb = 0;
    #pragma unroll 1
    for (int r = 0; r < KNN; ++r) {
        float d = dh[0]; int i = ih[0];
        #pragma unroll
        for (int s = 1; s < 64; s <<= 1) {
            float d2 = __shfl_xor(d, s); int i2 = __shfl_xor(i, s);
            if (d2 < d || (d2 == d && i2 < i)) { d = d2; i = i2; }
        }
        if (lane == r) mynb = i;
        if (ih[0] == i) {
            #pragma unroll
            for (int j = 0; j < 15; ++j) { dh[j] = dh[j + 1]; ih[j] = ih[j + 1]; }
            dh[15] = 3.4e38f; ih[15] = 0x7fffffff;
        }
    }
    mynb = min(max(mynb, 0), NPTS - 1);
    float bk_r = bk[lane], bp1_r = bp1[lane], bp2_r = bp2[lane];
    float bt1_r = bt1[lane], bt2_r = bt2[lane], ba_r = ba[lane];
    float wp1_0 = Wp1[lane], wp1_1 = Wp1[64 + lane];
    float wp1_2 = Wp1[128 + lane], wp1_3 = Wp1[192 + lane];
    float f = features[(size_t)p * HDIM + lane];
    float x = bk_r;
    #pragma unroll 8
    for (int c = 0; c < 64; ++c) x += __shfl(f, c) * sWk[c * 64 + lane];
    float q = 0.f;
    #pragma unroll 8
    for (int c = 0; c < 64; ++c) q += __shfl(x, c) * Wq[c * 64 + lane];
    float xq = (lane < 4) ? xyzp[(size_t)p * 4 + lane] : 0.f;
    float sm_m = -3.4e38f, sm_s = 0.f, sm_r = 0.f;
    #pragma unroll 1
    for (int j = 0; j < KNN; ++j) {
        int m = __shfl(mynb, j);
        int nb = b * NPTS + m;
        float fm = features[(size_t)nb * HDIM + lane];
        float xm = bk_r;
        #pragma unroll 8
        for (int c = 0; c < 64; ++c) xm += __shfl(fm, c) * sWk[c * 64 + lane];
        float km = 0.f, vm = 0.f;
        #pragma unroll 8
        for (int c = 0; c < 64; ++c) {
            float xc = __shfl(xm, c);
            km += xc * sWks[c * 64 + lane];
            vm += xc * sWv[c * 64 + lane];
        }
        float xn = (lane < 4) ? xyzp[(size_t)nb * 4 + lane] : 0.f;
        float rel = xq - xn;
        float a = bp1_r + __shfl(rel, 0) * wp1_0 + __shfl(rel, 1) * wp1_1
                        + __shfl(rel, 2) * wp1_2 + __shfl(rel, 3) * wp1_3;
        float pe1 = fmaxf(a, 0.f);
        float pe2 = bp2_r;
        #pragma unroll 8
        for (int c = 0; c < 64; ++c) pe2 += __shfl(pe1, c) * Wp2[c * 64 + lane];
        float ah = q - km + pe2;
        float t1 = bt1_r;
        #pragma unroll 8
        for (int c = 0; c < 64; ++c) t1 += __shfl(ah, c) * Wt1[c * 64 + lane];
        t1 = fmaxf(t1, 0.f);
        float lg = bt2_r;
        #pragma unroll 8
        for (int c = 0; c < 64; ++c) lg += __shfl(t1, c) * Wt2[c * 64 + lane];
        lg *= 0.125f;
        float vp = vm + pe2;
        float nm = fmaxf(sm_m, lg);
        float ea = fast_exp(sm_m - nm);
        float eb = fast_exp(lg - nm);
        sm_s = sm_s * ea + eb;
        sm_r = sm_r * ea + eb * vp;
        sm_m = nm;
    }
    float res = sm_r / sm_s;
    float o = ba_r;
    #pragma unroll 8
    for (int c = 0; c < 64; ++c) o += __shfl(res, c) * Wa[c * 64 + lane];
    out[(size_t)p * HDIM + lane] = o + f;
}

// ---------------------------------------------------------------------------
extern "C" void kernel_launch(void* const* d_in, const int* in_sizes, int n_in,
                              void* d_out, int out_size, void* d_ws, size_t ws_size,
                              hipStream_t stream)
{
    (void)in_sizes; (void)n_in; (void)out_size;
    const float* xyzp     = (const float*)d_in[0];
    const float* features = (const float*)d_in[1];
    const float* Wk  = (const float*)d_in[2];
    const float* bk  = (const float*)d_in[3];
    const float* Wq  = (const float*)d_in[4];
    const float* Wks = (const float*)d_in[5];
    const float* Wv  = (const float*)d_in[6];
    const float* Wp1 = (const float*)d_in[7];
    const float* bp1 = (const float*)d_in[8];
    const float* Wp2 = (const float*)d_in[9];
    const float* bp2 = (const float*)d_in[10];
    const float* Wt1 = (const float*)d_in[11];
    const float* bt1 = (const float*)d_in[12];
    const float* Wt2 = (const float*)d_in[13];
    const float* bt2 = (const float*)d_in[14];
    const float* Wa  = (const float*)d_in[15];
    const float* ba  = (const float*)d_in[16];
    float* out = (float*)d_out;

    const size_t qkv_bytes = (size_t)2 * NPTS * HDIM * 4;   // 4 MB each
    const size_t need = 3 * qkv_bytes + 3 * 4096 * 2;       // 12 MB + 24 KB

    if (ws_size >= need) {
        char* ws = (char*)d_ws;
        float* qw = (float*)ws;
        float* kw = (float*)(ws + qkv_bytes);
        float* vw = (float*)(ws + 2 * qkv_bytes);
        unsigned short* fragw = (unsigned short*)(ws + 3 * qkv_bytes);

        prefrag_kernel<<<48, 256, 0, stream>>>(Wp2, Wt1, Wt2, fragw);
        proj_kernel<<<(2 * NPTS) / 4, 256, 0, stream>>>(
            features, Wk, bk, Wq, Wks, Wv, qw, kw, vw);
        LocalTransformer_80513456931527_kernel<<<(2 * NPTS) / 4, 256, 0, stream>>>(
            xyzp, features, Wp1, bp1, bp2, bt1, bt2, Wa, ba,
            qw, kw, vw, fragw, out);
    } else {
        fused_fallback_kernel<<<(2 * NPTS) / 4, 256, 0, stream>>>(
            xyzp, features, Wk, bk, Wq, Wks, Wv,
            Wp1, bp1, Wp2, bp2, Wt1, bt1, Wt2, bt2, Wa, ba, out);
    }
}